// Round 7
// baseline (574.676 us; speedup 1.0000x reference)
//
#include <hip/hip_runtime.h>

// GaussianActionField: out[b][k][y] = sum_n exp(-(x[b]·P[n,:,k] - pos[n]·P[n,:,k])^2 / (2 sigma[n,k]^2)) * color[n][y]
// B=256 N=65536 XD=32 YD=64 K=8. sigma=0.01 -> ~0.74% of (b,n,k) pass g>2^-40.
// gaf_pre:    meta[n][k] = (posP, -log2e/(2 s^2))  (4 MB table in ws)
// gaf_main:   block = 64 b x 1024 n. Exact-split bf16 MFMA screen (x 3-way, P 2-way,
//             5 MFMA/tile, |err| ~2e-5). Candidates -> rotating LDS queue -> drained
//             next chunk as ds_add_f32 into a 128 KB LDS accumulator acc[64][8][64].
//             No global atomics, no scattered stores. Block writes one coalesced partial.
// gaf_reduce: out = sum over NR partials.

typedef __attribute__((ext_vector_type(8))) short short8;
typedef __attribute__((ext_vector_type(4))) float f32x4;

#define NTOT   65536
#define XD     32
#define YD     64
#define KK     8
#define BB     256
#define CN     8          // n per chunk
#define NKC    (CN*KK)    // 64 nk columns per chunk
#define TPB    512        // 8 waves
#define SETS   4          // b-sets (64 b each)
#define BT     64         // b per block
#define PBS    40         // LDS bf16 row stride (80B, 16B-aligned, 2-way banks max)
#define QCAP   256        // queue entries per buffer (Poisson mean ~30)
#define META_BYTES (NTOT*KK*8)        // float2 table = 4 MB
#define PART_FLOATS (BT*KK*YD)        // 32768 floats = 128 KB per block

__device__ __forceinline__ unsigned short f2bf(float f) {   // fp32 -> bf16 RNE
  unsigned u = __float_as_uint(f);
  u += 0x7FFFu + ((u >> 16) & 1u);
  return (unsigned short)(u >> 16);
}
__device__ __forceinline__ float bf2f(unsigned short h) {
  return __uint_as_float((unsigned)h << 16);
}
__device__ __forceinline__ void split2(float v, unsigned short& h0, unsigned short& h1) {
  h0 = f2bf(v);
  h1 = f2bf(v - bf2f(h0));
}
__device__ __forceinline__ void split3(float v, unsigned short& h0,
                                       unsigned short& h1, unsigned short& h2) {
  h0 = f2bf(v);
  float r1 = v - bf2f(h0);
  h1 = f2bf(r1);
  h2 = f2bf(r1 - bf2f(h1));
}

// ---------------- pre: posP + exponent scale table ----------------
__global__ __launch_bounds__(256)
void gaf_pre(const float* __restrict__ pos, const float* __restrict__ proj,
             const float* __restrict__ sig, float2* __restrict__ meta) {
  int gid = blockIdx.x * 256 + threadIdx.x;    // (n,k) flat, 524288 total
  int n = gid >> 3, k = gid & 7;
  const float*  pk = proj + (size_t)n * XD * KK + k;   // stride-8 column
  const float4* pg = (const float4*)(pos + (size_t)n * XD);
  float d = 0.f;
#pragma unroll
  for (int j = 0; j < 8; ++j) {
    float4 v = pg[j];
    d = fmaf(v.x, pk[(4*j+0)*KK], d);
    d = fmaf(v.y, pk[(4*j+1)*KK], d);
    d = fmaf(v.z, pk[(4*j+2)*KK], d);
    d = fmaf(v.w, pk[(4*j+3)*KK], d);
  }
  float s = sig[gid];
  meta[gid] = make_float2(d, -0.72134752044448169f / (s * s));
}

// ---------------- main: fused screen + LDS accumulate ----------------
__global__ __launch_bounds__(TPB, 1)
void gaf_main(const float* __restrict__ x, const float* __restrict__ proj,
              const float* __restrict__ colr, const float2* __restrict__ meta,
              float* __restrict__ partial, int NR) {
  __shared__ float          acc[BT][KK][YD];       // 131072 B
  __shared__ unsigned short sP0[2][NKC][PBS];      // 10240 B
  __shared__ unsigned short sP1[2][NKC][PBS];      // 10240 B
  __shared__ float2         sMeta[2][NKC];         //  1024 B
  __shared__ int2           sQ[3][QCAP];           //  6144 B
  __shared__ unsigned       sQn[3];

  const int t = threadIdx.x, l = t & 63, w = t >> 6;
  const int s  = blockIdx.x & (SETS - 1);
  const int nr = blockIdx.x >> 2;
  const int nspan = NTOT / NR, nchunks = nspan / CN;
  const int nbase = nr * nspan;
  const f32x4 kZero = {0.f, 0.f, 0.f, 0.f};

  // zero acc
  {
    float4 z = {0.f, 0.f, 0.f, 0.f};
    float4* a4 = (float4*)&acc[0][0][0];
#pragma unroll
    for (int r = 0; r < PART_FLOATS / 4 / TPB; ++r) a4[t + r * TPB] = z;
  }
  if (t < 3) sQn[t] = 0u;

  // A fragments: x rows 3-way split (wave w owns b-tile w&3)
  const int i0 = (l >> 4) << 3;
  const int bt = w & 3;
  short8 a0, a1, a2;
  {
    const int brow = s * BT + bt * 16 + (l & 15);
    const float4* xr = (const float4*)(x + (size_t)brow * XD + i0);
    float4 u0 = xr[0], u1 = xr[1];
    float xv[8] = {u0.x, u0.y, u0.z, u0.w, u1.x, u1.y, u1.z, u1.w};
#pragma unroll
    for (int j = 0; j < 8; ++j) {
      unsigned short h0, h1, h2;
      split3(xv[j], h0, h1, h2);
      a0[j] = (short)h0; a1[j] = (short)h1; a2[j] = (short)h2;
    }
  }

  auto stageChunk = [&](int buf, float4 v) {
    int nn = t >> 6, i = (t & 63) >> 1, nk = nn * KK + ((t & 1) << 2);
    unsigned short h0, h1;
    split2(v.x, h0, h1); sP0[buf][nk+0][i] = h0; sP1[buf][nk+0][i] = h1;
    split2(v.y, h0, h1); sP0[buf][nk+1][i] = h0; sP1[buf][nk+1][i] = h1;
    split2(v.z, h0, h1); sP0[buf][nk+2][i] = h0; sP1[buf][nk+2][i] = h1;
    split2(v.w, h0, h1); sP0[buf][nk+3][i] = h0; sP1[buf][nk+3][i] = h1;
  };

  auto appendC = [&](f32x4 S, float2 mt, int col, int qa) {
#pragma unroll
    for (int r = 0; r < 4; ++r) {
      float d  = S[r] - mt.x;
      float t0 = d * d * mt.y;               // mt.y < 0
      bool pass = (t0 > -40.f);              // g >= 2^-40
      unsigned long long msk = __ballot(pass);
      if (msk) {                             // wave-uniform
        unsigned base = 0u;
        if (l == 0) base = atomicAdd(&sQn[qa], (unsigned)__popcll(msk));
        base = __shfl(base, 0);
        if (pass) {
          unsigned off = base + __builtin_amdgcn_mbcnt_hi((unsigned)(msk >> 32),
                          __builtin_amdgcn_mbcnt_lo((unsigned)msk, 0u));
          if (off < QCAP) {
            int bl = bt * 16 + ((l >> 4) << 2) + r;      // C/D: row=(l>>4)*4+r
            sQ[qa][off] = make_int2((bl << 6) | ((col & 7) << 3) | (col >> 3),
                                    __float_as_int(t0));
          }
        }
      }
    }
  };

  auto drainQ = [&](int qb, int nbd) {       // 4-deep pipelined drain
    int m = (int)sQn[qb]; if (m > QCAP) m = QCAP;
    float* accF = &acc[0][0][0];
    int2 qA, qB, qC, qD; float cA, cB, cC, cD;
    bool vA = (w < m), vB = (w + 8 < m), vC = (w + 16 < m), vD = (w + 24 < m);
    if (vA) { qA = sQ[qb][w];      cA = colr[(size_t)(nbd + (qA.x & 7)) * YD + l]; }
    if (vB) { qB = sQ[qb][w + 8];  cB = colr[(size_t)(nbd + (qB.x & 7)) * YD + l]; }
    if (vC) { qC = sQ[qb][w + 16]; cC = colr[(size_t)(nbd + (qC.x & 7)) * YD + l]; }
    if (vD) { qD = sQ[qb][w + 24]; cD = colr[(size_t)(nbd + (qD.x & 7)) * YD + l]; }
    if (vA) atomicAdd(&accF[(qA.x >> 3) * YD + l],
                      __builtin_amdgcn_exp2f(__int_as_float(qA.y)) * cA);
    if (vB) atomicAdd(&accF[(qB.x >> 3) * YD + l],
                      __builtin_amdgcn_exp2f(__int_as_float(qB.y)) * cB);
    if (vC) atomicAdd(&accF[(qC.x >> 3) * YD + l],
                      __builtin_amdgcn_exp2f(__int_as_float(qC.y)) * cC);
    if (vD) atomicAdd(&accF[(qD.x >> 3) * YD + l],
                      __builtin_amdgcn_exp2f(__int_as_float(qD.y)) * cD);
    for (int e = w + 32; e < m; e += 8) {    // rare stragglers
      int2 q = sQ[qb][e];
      float cv = colr[(size_t)(nbd + (q.x & 7)) * YD + l];
      atomicAdd(&accF[(q.x >> 3) * YD + l],
                __builtin_amdgcn_exp2f(__int_as_float(q.y)) * cv);
    }
  };

  // stage chunk 0
  {
    float4 v = ((const float4*)(proj + (size_t)nbase * XD * KK))[t];
    stageChunk(0, v);
    if (t < NKC) sMeta[0][t] = meta[(size_t)nbase * KK + t];
  }
  __syncthreads();

  for (int c = 0; c < nchunks; ++c) {
    const int cur = c & 1;
    const int qa = c % 3, qd = (c + 2) % 3, qr = (c + 1) % 3;
    const int n0 = nbase + c * CN;
    const bool havePf = (c + 1 < nchunks);
    float4 pf; float2 mf;
    if (havePf) {                            // prefetch next chunk early
      pf = ((const float4*)(proj + (size_t)(n0 + CN) * XD * KK))[t];
      if (t < NKC) mf = meta[(size_t)(n0 + CN) * KK + t];
    }
    if (t == 0) sQn[qr] = 0u;                // qr untouched by anyone this phase

    // screen: 2 interleaved 5-MFMA chains per wave
    {
      const int colA = ((w >> 2) * 2) * 16 + (l & 15);
      const int colB = colA + 16;
      short8 b0A = *(const short8*)&sP0[cur][colA][i0];
      short8 b1A = *(const short8*)&sP1[cur][colA][i0];
      short8 b0B = *(const short8*)&sP0[cur][colB][i0];
      short8 b1B = *(const short8*)&sP1[cur][colB][i0];
      f32x4 SA = __builtin_amdgcn_mfma_f32_16x16x32_bf16(a2, b0A, kZero, 0, 0, 0);
      f32x4 SB = __builtin_amdgcn_mfma_f32_16x16x32_bf16(a2, b0B, kZero, 0, 0, 0);
      SA = __builtin_amdgcn_mfma_f32_16x16x32_bf16(a1, b1A, SA, 0, 0, 0);
      SB = __builtin_amdgcn_mfma_f32_16x16x32_bf16(a1, b1B, SB, 0, 0, 0);
      SA = __builtin_amdgcn_mfma_f32_16x16x32_bf16(a0, b1A, SA, 0, 0, 0);
      SB = __builtin_amdgcn_mfma_f32_16x16x32_bf16(a0, b1B, SB, 0, 0, 0);
      SA = __builtin_amdgcn_mfma_f32_16x16x32_bf16(a1, b0A, SA, 0, 0, 0);
      SB = __builtin_amdgcn_mfma_f32_16x16x32_bf16(a1, b0B, SB, 0, 0, 0);
      SA = __builtin_amdgcn_mfma_f32_16x16x32_bf16(a0, b0A, SA, 0, 0, 0);
      SB = __builtin_amdgcn_mfma_f32_16x16x32_bf16(a0, b0B, SB, 0, 0, 0);
      float2 mtA = sMeta[cur][colA], mtB = sMeta[cur][colB];
      appendC(SA, mtA, colA, qa);
      appendC(SB, mtB, colB, qa);
    }

    if (c > 0) drainQ(qd, n0 - CN);          // drain previous chunk's candidates

    if (havePf) {                            // split + write next chunk
      stageChunk(cur ^ 1, pf);
      if (t < NKC) sMeta[cur ^ 1][t] = mf;
    }
    __syncthreads();
  }
  drainQ((nchunks - 1) % 3, nbase + (nchunks - 1) * CN);
  __syncthreads();

  // write partial tile (coalesced)
  {
    float* pb = partial + (size_t)blockIdx.x * PART_FLOATS;
    float4* src = (float4*)&acc[0][0][0];
    float4* dst = (float4*)pb;
#pragma unroll
    for (int r = 0; r < PART_FLOATS / 4 / TPB; ++r)
      dst[t + r * TPB] = src[t + r * TPB];
  }
}

// ---------------- reduce: out = sum of NR partials ----------------
__global__ __launch_bounds__(256)
void gaf_reduce(const float* __restrict__ partial, float* __restrict__ out, int NR) {
  const int b = blockIdx.x;            // global b, 0..255
  const int s = b >> 6, bl = b & 63;
  const int t = threadIdx.x;
#pragma unroll
  for (int h = 0; h < 2; ++h) {
    int e = t + h * 256;               // (k,y) flat, 0..511
    float sum = 0.f;
#pragma unroll 8
    for (int nr = 0; nr < NR; ++nr)
      sum += partial[(size_t)(nr * SETS + s) * PART_FLOATS + bl * (KK * YD) + e];
    out[(size_t)b * (KK * YD) + e] = sum;
  }
}

extern "C" void kernel_launch(void* const* d_in, const int* in_sizes, int n_in,
                              void* d_out, int out_size, void* d_ws, size_t ws_size,
                              hipStream_t stream) {
  const float* x    = (const float*)d_in[0];
  const float* pos  = (const float*)d_in[1];
  const float* proj = (const float*)d_in[2];
  const float* colr = (const float*)d_in[3];
  const float* sig  = (const float*)d_in[4];
  float* out = (float*)d_out;

  float2* meta   = (float2*)d_ws;
  float* partial = (float*)((char*)d_ws + META_BYTES);

  int NR = 64;                         // n-parallel partials; 4.19MB + NR*0.52MB of ws
  while (NR > 4 && META_BYTES + (size_t)NR * SETS * PART_FLOATS * 4 > ws_size) NR >>= 1;

  gaf_pre<<<(NTOT * KK) / 256, 256, 0, stream>>>(pos, proj, sig, meta);
  gaf_main<<<SETS * NR, TPB, 0, stream>>>(x, proj, colr, meta, partial, NR);
  gaf_reduce<<<BB, 256, 0, stream>>>(partial, out, NR);
}

// Round 8
// 182.657 us; speedup vs baseline: 3.1462x; 3.1462x over previous
//
#include <hip/hip_runtime.h>

// GaussianActionField: out[b][k][y] = sum_n exp(-(x[b]·P[n,:,k] - posP[n][k])^2 / (2 s^2)) * color[n][y]
// B=256 N=65536 XD=32 YD=64 K=8.
// Fully dense, attention-style: screen GEMM (swapped: S^T = P·x, exact via 2x2 bf16 split,
// 4 MFMA) -> in-register exp -> cvt_pk to bf16 -> PV GEMM (out^T = color^T · G) where the
// screen C-fragment IS the PV B-fragment (zero data movement). K=16 PV emulated by
// zero-padding the 16x16x32 intrinsic. No sparsity, no atomics, no worklists.
// gaf_pre: meta[n][k] = (posP, -log2e/(2 s^2)) table (4 MB in ws).
// gaf_main: block = 64 b x (N/NR) n; 8 waves = 4 b-tiles x 2 k-halves; partial in ws.
// gaf_reduce: out = sum over NR partials.

typedef __attribute__((ext_vector_type(8))) short short8;
typedef __attribute__((ext_vector_type(4))) float f32x4;

#define NTOT   65536
#define XD     32
#define YD     64
#define KK     8
#define META_BYTES (NTOT*KK*8)     // float2 per (n,k) = 4 MB
#define PART_FLOATS 32768          // per block: 64b x 8k x 64y
#define NCHUNKS 2048               // 32-n chunks

__device__ __forceinline__ unsigned short f2bf(float f) {   // fp32 -> bf16 RNE
  unsigned u = __float_as_uint(f);
  u += 0x7FFFu + ((u >> 16) & 1u);
  return (unsigned short)(u >> 16);
}

union FragU { unsigned u[4]; short8 s8; };

// ---------------- pre: posP + exponent scale table ----------------
__global__ __launch_bounds__(256)
void gaf_pre(const float* __restrict__ pos, const float* __restrict__ proj,
             const float* __restrict__ sig, float2* __restrict__ meta) {
  int gid = blockIdx.x * 256 + threadIdx.x;    // (n,k) flat
  int n = gid >> 3, k = gid & 7;
  const float*  pk = proj + (size_t)n * XD * KK + k;
  const float4* pg = (const float4*)(pos + (size_t)n * XD);
  float d = 0.f;
#pragma unroll
  for (int j = 0; j < 8; ++j) {
    float4 v = pg[j];
    d = fmaf(v.x, pk[(4*j+0)*KK], d);
    d = fmaf(v.y, pk[(4*j+1)*KK], d);
    d = fmaf(v.z, pk[(4*j+2)*KK], d);
    d = fmaf(v.w, pk[(4*j+3)*KK], d);
  }
  float s = sig[gid];
  meta[gid] = make_float2(d, -0.72134752044448169f / (s * s));
}

// ---------------- main: dense screen->exp->PV, register-fused ----------------
__global__ __launch_bounds__(512, 4)
void gaf_main(const float* __restrict__ x, const float* __restrict__ proj,
              const float* __restrict__ colr, const float2* __restrict__ meta,
              float* __restrict__ partial, int NCH) {
  // sPool: sPb0[256][40], sPb1[256][40] (u16), sCol[64][40] (u16); epilogue overlays it.
  __shared__ unsigned short sPool[2*256*40 + 64*40];   // 46080 B
  __shared__ float sPosP[8][36];
  __shared__ float sInv[8][36];
  unsigned short (*sPb0)[40] = (unsigned short(*)[40])sPool;
  unsigned short (*sPb1)[40] = (unsigned short(*)[40])(sPool + 256*40);
  unsigned short (*sCol)[40] = (unsigned short(*)[40])(sPool + 2*256*40);

  const int t = threadIdx.x, l = t & 63, w = t >> 6;
  const int sblk = blockIdx.x & 3, nr = blockIdx.x >> 2;
  const int bt = w & 3, k0 = (w >> 2) * 4;     // wave: b-tile bt, k's k0..k0+3
  const int lc = l & 15, lg = l >> 4;          // lane col / group
  const int cbeg = nr * NCH;
  int cend = cbeg + NCH; if (cend > NCHUNKS) cend = NCHUNKS;

  float* pb = partial + (size_t)blockIdx.x * PART_FLOATS;
  if (cbeg >= cend) {                          // idle block: zero partial
    float4 z = {0.f,0.f,0.f,0.f};
#pragma unroll
    for (int r = 0; r < PART_FLOATS/4/512; ++r) ((float4*)pb)[t + r*512] = z;
    return;
  }

  // x B-fragments (2-way bf16 split), wave's b-tile: lane holds x[b=lc][i=lg*8+j]
  short8 xf0, xf1;
  {
    const int brow = sblk*64 + bt*16 + lc;
    const float4* xr = (const float4*)(x + (size_t)brow*XD + lg*8);
    float4 u0 = xr[0], u1 = xr[1];
    float xv[8] = {u0.x,u0.y,u0.z,u0.w,u1.x,u1.y,u1.z,u1.w};
#pragma unroll
    for (int j = 0; j < 8; ++j) {
      unsigned u = __float_as_uint(xv[j]);
      unsigned short h0 = (unsigned short)(u >> 16);        // trunc
      float r1 = xv[j] - __uint_as_float(u & 0xFFFF0000u);  // exact
      xf0[j] = (short)h0;
      xf1[j] = (short)f2bf(r1);
    }
  }

  f32x4 acc[4][4];                             // [k-kk][y-subtile]
#pragma unroll
  for (int a = 0; a < 4; ++a)
#pragma unroll
    for (int b = 0; b < 4; ++b) acc[a][b] = (f32x4){0.f,0.f,0.f,0.f};

  // prefetch color+meta for first chunk
  float4 cpf; float2 mpf;
  {
    int n0 = cbeg * 32;
    cpf = ((const float4*)(colr + (size_t)n0*YD))[t];
    if (t < 256) mpf = meta[(size_t)n0*KK + t];
  }

  for (int c = cbeg; c < cend; ++c) {
    const int n0 = c * 32;
    // ---- stage chunk c ----
    float4 pv0, pv1, pv2, pv3;
    {
      const float4* Pg = (const float4*)(proj + (size_t)n0 * XD * KK);
      pv0 = Pg[t]; pv1 = Pg[t+512]; pv2 = Pg[t+1024]; pv3 = Pg[t+1536];
    }
    { // colorT: [y][n] bf16 (1-way)
      int n = t >> 4, y4 = (t & 15) * 4;
      sCol[y4+0][n] = f2bf(cpf.x);
      sCol[y4+1][n] = f2bf(cpf.y);
      sCol[y4+2][n] = f2bf(cpf.z);
      sCol[y4+3][n] = f2bf(cpf.w);
    }
    if (t < 256) { sPosP[t&7][t>>3] = mpf.x; sInv[t&7][t>>3] = mpf.y; }
    { // P 2-way split -> sPb0/sPb1 [k*32+n][i]
      float4 pv[4] = {pv0, pv1, pv2, pv3};
#pragma unroll
      for (int r = 0; r < 4; ++r) {
        int f = t + r*512;
        int nn = f >> 6, i = (f & 63) >> 1, kk4 = (f & 1) * 4;
        float vj[4] = {pv[r].x, pv[r].y, pv[r].z, pv[r].w};
#pragma unroll
        for (int j = 0; j < 4; ++j) {
          unsigned u = __float_as_uint(vj[j]);
          int row = (kk4 + j)*32 + nn;
          sPb0[row][i] = (unsigned short)(u >> 16);
          sPb1[row][i] = f2bf(vj[j] - __uint_as_float(u & 0xFFFF0000u));
        }
      }
    }
    __syncthreads();                           // LDS ready
    if (c + 1 < cend) {                        // prefetch next color+meta
      int n1 = (c+1) * 32;
      cpf = ((const float4*)(colr + (size_t)n1*YD))[t];
      if (t < 256) mpf = meta[(size_t)n1*KK + t];
    }

    // ---- compute: screen (S^T) -> exp -> PV, all register-local ----
#pragma unroll
    for (int kk = 0; kk < 4; ++kk) {
      const int k = k0 + kk;
#pragma unroll
      for (int s = 0; s < 2; ++s) {
        const int prow = k*32 + s*16 + lc;
        short8 p0 = *(const short8*)&sPb0[prow][lg*8];
        short8 p1 = *(const short8*)&sPb1[prow][lg*8];
        f32x4 S = (f32x4){0.f,0.f,0.f,0.f};
        S = __builtin_amdgcn_mfma_f32_16x16x32_bf16(p1, xf1, S, 0, 0, 0);
        S = __builtin_amdgcn_mfma_f32_16x16x32_bf16(p1, xf0, S, 0, 0, 0);
        S = __builtin_amdgcn_mfma_f32_16x16x32_bf16(p0, xf1, S, 0, 0, 0);
        S = __builtin_amdgcn_mfma_f32_16x16x32_bf16(p0, xf0, S, 0, 0, 0);
        // tail: g_r = exp2((S_r - posP)^2 * inv)   (underflow -> 0 handles cutoff)
        float4 pp = *(const float4*)&sPosP[k][s*16 + lg*4];
        float4 iv = *(const float4*)&sInv[k][s*16 + lg*4];
        float d0 = S[0]-pp.x, d1 = S[1]-pp.y, d2 = S[2]-pp.z, d3 = S[3]-pp.w;
        float g0 = __builtin_amdgcn_exp2f(d0*d0*iv.x);
        float g1 = __builtin_amdgcn_exp2f(d1*d1*iv.y);
        float g2 = __builtin_amdgcn_exp2f(d2*d2*iv.z);
        float g3 = __builtin_amdgcn_exp2f(d3*d3*iv.w);
        unsigned u0, u1;
        asm("v_cvt_pk_bf16_f32 %0, %1, %2" : "=v"(u0) : "v"(g0), "v"(g1));
        asm("v_cvt_pk_bf16_f32 %0, %1, %2" : "=v"(u1) : "v"(g2), "v"(g3));
        FragU gb; gb.u[0] = u0; gb.u[1] = u1; gb.u[2] = 0u; gb.u[3] = 0u;
        // PV: out^T[y][b] += color^T · G  (K=16 zero-padded into 16x16x32)
#pragma unroll
        for (int ys = 0; ys < 4; ++ys) {
          const uint2 a = *(const uint2*)&sCol[ys*16 + lc][s*16 + lg*4];
          FragU af; af.u[0] = a.x; af.u[1] = a.y; af.u[2] = 0u; af.u[3] = 0u;
          acc[kk][ys] = __builtin_amdgcn_mfma_f32_16x16x32_bf16(af.s8, gb.s8,
                                                                acc[kk][ys], 0, 0, 0);
        }
      }
    }
    __syncthreads();                           // compute done; next stage may overwrite
  }

  // ---- epilogue: transpose acc via LDS, coalesced partial write ----
  float* epi = (float*)sPool + w * (64*17);    // per-wave [64y][17] f32
#pragma unroll
  for (int kk = 0; kk < 4; ++kk) {
    const int k = k0 + kk;
#pragma unroll
    for (int ys = 0; ys < 4; ++ys) {
#pragma unroll
      for (int r = 0; r < 4; ++r)
        epi[(ys*16 + lg*4 + r)*17 + lc] = acc[kk][ys][r];
    }
    __syncthreads();
#pragma unroll
    for (int it = 0; it < 4; ++it) {
      int bi = it*4 + lg, y0 = lc*4;
      float4 v = { epi[(y0+0)*17 + bi], epi[(y0+1)*17 + bi],
                   epi[(y0+2)*17 + bi], epi[(y0+3)*17 + bi] };
      *(float4*)&pb[(size_t)(bt*16 + bi)*512 + k*64 + y0] = v;
    }
    __syncthreads();
  }
}

// ---------------- reduce: out = sum of NR partials ----------------
__global__ __launch_bounds__(512)
void gaf_reduce(const float* __restrict__ partial, float* __restrict__ out, int NR) {
  const int b = blockIdx.x;                    // global b
  const int s = b >> 6, bl = b & 63;
  const int t = threadIdx.x;                   // (k,y) flat 0..511
  float a0 = 0.f, a1 = 0.f, a2 = 0.f, a3 = 0.f;
  int nr = 0;
  for (; nr + 4 <= NR; nr += 4) {
    a0 += partial[(size_t)((nr+0)*4 + s)*PART_FLOATS + bl*512 + t];
    a1 += partial[(size_t)((nr+1)*4 + s)*PART_FLOATS + bl*512 + t];
    a2 += partial[(size_t)((nr+2)*4 + s)*PART_FLOATS + bl*512 + t];
    a3 += partial[(size_t)((nr+3)*4 + s)*PART_FLOATS + bl*512 + t];
  }
  for (; nr < NR; ++nr)
    a0 += partial[(size_t)(nr*4 + s)*PART_FLOATS + bl*512 + t];
  out[(size_t)b*512 + t] = (a0 + a1) + (a2 + a3);
}

extern "C" void kernel_launch(void* const* d_in, const int* in_sizes, int n_in,
                              void* d_out, int out_size, void* d_ws, size_t ws_size,
                              hipStream_t stream) {
  const float* x    = (const float*)d_in[0];
  const float* pos  = (const float*)d_in[1];
  const float* proj = (const float*)d_in[2];
  const float* colr = (const float*)d_in[3];
  const float* sig  = (const float*)d_in[4];
  float* out = (float*)d_out;

  float2* meta   = (float2*)d_ws;
  float*  partial = (float*)((char*)d_ws + META_BYTES);

  size_t avail = (ws_size > META_BYTES) ? ws_size - META_BYTES : 0;
  int NR = (int)(avail / (4ull * PART_FLOATS * 4ull));  // 512 KB per NR step
  if (NR > 128) NR = 128;
  if (NR < 1)  NR = 1;
  int NCH = (NCHUNKS + NR - 1) / NR;

  gaf_pre<<<(NTOT*KK)/256, 256, 0, stream>>>(pos, proj, sig, meta);
  gaf_main<<<4*NR, 512, 0, stream>>>(x, proj, colr, meta, partial, NCH);
  gaf_reduce<<<256, 512, 0, stream>>>(partial, out, NR);
}